// Round 10
// baseline (709.573 us; speedup 1.0000x reference)
//
#include <hip/hip_runtime.h>

// Problem constants
#define NB      32      // batch
#define INF     128     // in_flt
#define NPIX    64      // N
#define TSP     16      // t
#define OUTF    32      // out_flt
#define FF      16      // intermediate features
#define D_IN    768     // 3*t*t
#define D_OUT   8192    // out_flt*t*t
#define NCOL    (D_OUT*FF)   // 131072
#define OUTCH   160     // in_flt + out_flt
#define BSTRIDE 655360  // 160*64*64 floats per batch in d_out
#define MOFF    524288  // 128*64*64: offset of out_a region per batch (M scratch)

// K1: fused strided conv (128ch,4x4,stride4 -> 3ch) + x->out concat copy.
__global__ __launch_bounds__(256) void k1_conv_copy(
    const float* __restrict__ x, const float* __restrict__ wc,
    float* __restrict__ out, float* __restrict__ At)
{
    __shared__ float sW[3*128*16];     // w_conv, 24 KB
    __shared__ float sP[16][16][3];    // partials [icg][j][c3]
    const int b   = blockIdx.x >> 4;
    const int oi  = blockIdx.x & 15;
    const int tid = threadIdx.x;
    for (int idx = tid; idx < 6144; idx += 256) sW[idx] = wc[idx];
    __syncthreads();
    const int icg = tid >> 4;          // 0..15 -> ic block of 8
    const int j   = tid & 15;          // output col
    float a0 = 0.f, a1 = 0.f, a2 = 0.f;
    for (int ic8 = 0; ic8 < 8; ++ic8) {
        const int ic = icg*8 + ic8;
        #pragma unroll
        for (int ki = 0; ki < 4; ++ki) {
            const int row = 4*oi + ki;
            const float4 xv = *(const float4*)(x + ((size_t)(b*INF+ic)*NPIX + row)*NPIX + 4*j);
            *(float4*)(out + ((size_t)(b*OUTCH+ic)*NPIX + row)*NPIX + 4*j) = xv;
            const float* w0 = sW + ((0*INF+ic)*4 + ki)*4;
            const float* w1 = sW + ((1*INF+ic)*4 + ki)*4;
            const float* w2 = sW + ((2*INF+ic)*4 + ki)*4;
            a0 += xv.x*w0[0] + xv.y*w0[1] + xv.z*w0[2] + xv.w*w0[3];
            a1 += xv.x*w1[0] + xv.y*w1[1] + xv.z*w1[2] + xv.w*w1[3];
            a2 += xv.x*w2[0] + xv.y*w2[1] + xv.z*w2[2] + xv.w*w2[3];
        }
    }
    sP[icg][j][0] = a0; sP[icg][j][1] = a1; sP[icg][j][2] = a2;
    __syncthreads();
    if (tid < 48) {
        const int c3 = tid >> 4, jj = tid & 15;
        float s = 0.f;
        #pragma unroll
        for (int g = 0; g < 16; ++g) s += sP[g][jj][c3];
        const int k = c3*256 + oi*16 + jj;    // reshape(3,16,16) C-order
        At[k*32 + b] = s;
    }
}

// K2 v10: ROOT CAUSE found in R8/R9: the 4 bg-waves per col-range SHARE
// their T columns -> demand = 4x T = 1.61 GB; kernel was L1/L2-delivery
// bound on redundant traffic (R5's "unique col" comment was wrong: w&1
// gives only 2 ranges across 8 waves). FIX: raw s_barrier (NO waitcnt
// drain - control-only, data-independent) every 8 k-steps bounds the
// bg-waves' k-drift to 8 KB << 32 KB L1 -> L1 serves 3 of 4 reads,
// L2/HBM demand drops to ~402 MB. x3 reps for rocprof visibility
// (idempotent; de-amplify next round).
__global__ __launch_bounds__(512, 2) void k2_gemm(
    const float* __restrict__ At, const float* __restrict__ Tm,
    float* __restrict__ out)
{
    extern __shared__ float sA[];      // D_IN*32 floats = 96 KB
    const int tid = threadIdx.x;
    {   // stage all of At, coalesced float4
        const float4* src = (const float4*)At;
        float4* dst = (float4*)sA;
        #pragma unroll
        for (int i = 0; i < 12; ++i)
            dst[tid + i*512] = src[tid + i*512];
    }
    __syncthreads();
    const int w    = tid >> 6;                 // wave 0..7
    const int lane = tid & 63;
    const int bg   = w >> 1;                   // batch-group of 8 (wave-uniform)
    const int col4 = blockIdx.x*512 + (w & 1)*256 + lane*4;

    const float* tp    = Tm + col4;
    const float* aBase = sA + bg*8;            // wave-uniform -> ds broadcast

    for (int rep = 0; rep < 3; ++rep) {
        float acc[8][4];
        #pragma unroll
        for (int i = 0; i < 8; ++i)
            #pragma unroll
            for (int j = 0; j < 4; ++j) acc[i][j] = 0.f;

#define TLD(KK) (*(const float4*)(tp + (size_t)(KK)*NCOL))
#define FM32(T4, AL, AH) { \
  acc[0][0]+=AL.x*T4.x; acc[0][1]+=AL.x*T4.y; acc[0][2]+=AL.x*T4.z; acc[0][3]+=AL.x*T4.w; \
  acc[1][0]+=AL.y*T4.x; acc[1][1]+=AL.y*T4.y; acc[1][2]+=AL.y*T4.z; acc[1][3]+=AL.y*T4.w; \
  acc[2][0]+=AL.z*T4.x; acc[2][1]+=AL.z*T4.y; acc[2][2]+=AL.z*T4.z; acc[2][3]+=AL.z*T4.w; \
  acc[3][0]+=AL.w*T4.x; acc[3][1]+=AL.w*T4.y; acc[3][2]+=AL.w*T4.z; acc[3][3]+=AL.w*T4.w; \
  acc[4][0]+=AH.x*T4.x; acc[4][1]+=AH.x*T4.y; acc[4][2]+=AH.x*T4.z; acc[4][3]+=AH.x*T4.w; \
  acc[5][0]+=AH.y*T4.x; acc[5][1]+=AH.y*T4.y; acc[5][2]+=AH.y*T4.z; acc[5][3]+=AH.y*T4.w; \
  acc[6][0]+=AH.z*T4.x; acc[6][1]+=AH.z*T4.y; acc[6][2]+=AH.z*T4.z; acc[6][3]+=AH.z*T4.w; \
  acc[7][0]+=AH.w*T4.x; acc[7][1]+=AH.w*T4.y; acc[7][2]+=AH.w*T4.z; acc[7][3]+=AH.w*T4.w; }
#define STEP(J, TT) { \
    const float4 aL = *(const float4*)(aBase + (k0+(J))*32); \
    const float4 aH = *(const float4*)(aBase + (k0+(J))*32 + 4); \
    FM32(TT, aL, aH); TT = TLD(k0 + 8 + (J)); }
#define STEPE(J, TT) { \
    const float4 aL = *(const float4*)(aBase + (k0+(J))*32); \
    const float4 aH = *(const float4*)(aBase + (k0+(J))*32 + 4); \
    FM32(TT, aL, aH); }

        float4 t0=TLD(0), t1=TLD(1), t2=TLD(2), t3=TLD(3),
               t4=TLD(4), t5=TLD(5), t6=TLD(6), t7=TLD(7);

        int k0 = 0;
        for (; k0 < D_IN - 8; k0 += 8) {
            __builtin_amdgcn_s_barrier();   // drift limiter: no data handoff,
                                            // so no waitcnt drain needed
            STEP(0, t0) STEP(1, t1) STEP(2, t2) STEP(3, t3)
            STEP(4, t4) STEP(5, t5) STEP(6, t6) STEP(7, t7)
        }
        STEPE(0, t0) STEPE(1, t1) STEPE(2, t2) STEPE(3, t3)
        STEPE(4, t4) STEPE(5, t5) STEPE(6, t6) STEPE(7, t7)
#undef STEPE
#undef STEP
#undef FM32
#undef TLD

        #pragma unroll
        for (int bb = 0; bb < 8; ++bb)
            *(float4*)(out + (size_t)(bg*8 + bb)*BSTRIDE + MOFF + col4) =
                make_float4(acc[bb][0], acc[bb][1], acc[bb][2], acc[bb][3]);
    }
}

// K3: out[j,d] = sum_i exp(-sum_f |M[i,d,f]-M[j,d,f]|) - 1. (M in d_out slots)
__global__ __launch_bounds__(256) void k3_pairs(
    const float* __restrict__ outM, float* __restrict__ outS)
{
    extern __shared__ float sM[];      // 32*32*17 floats
    const int tid = threadIdx.x;
    const int dd0 = blockIdx.x * 32;
    for (int idx = tid; idx < 32*32*16; idx += 256) {
        const int i = idx >> 9, rem = idx & 511, d = rem >> 4, f = rem & 15;
        sM[(i*32 + d)*17 + f] =
            outM[(size_t)i*BSTRIDE + MOFF + (size_t)(dd0 + d)*16 + f];
    }
    __syncthreads();
    const int j = tid >> 3;
    for (int q = 0; q < 4; ++q) {
        const int d = (tid & 7) + q*8;
        float mj[16];
        const float* pj = sM + (j*32 + d)*17;
        #pragma unroll
        for (int f = 0; f < 16; ++f) mj[f] = pj[f];
        float acc = 0.f;
        for (int i = 0; i < 32; ++i) {
            const float* pi = sM + (i*32 + d)*17;
            float dist = 0.f;
            #pragma unroll
            for (int f = 0; f < 16; ++f) dist += fabsf(pi[f] - mj[f]);
            acc += __expf(-dist);
        }
        outS[(size_t)j*D_OUT + dd0 + d] = acc - 1.0f;
    }
}

// K4: ConvTranspose2d, stride==kernel -> no overlap.
__global__ __launch_bounds__(256) void k4_deconv(
    const float* __restrict__ outS, const float* __restrict__ wd,
    float* __restrict__ out)
{
    __shared__ float sO[32*256];       // [ic][si*16+sj]
    __shared__ float sWd[32*16];       // [ic][ki*4+kj]
    const int b   = blockIdx.x >> 5;
    const int oc  = blockIdx.x & 31;
    const int tid = threadIdx.x;
    for (int idx = tid; idx < 8192; idx += 256) sO[idx] = outS[(size_t)b*D_OUT + idx];
    for (int idx = tid; idx < 512; idx += 256) {
        const int ic = idx >> 4, r = idx & 15;
        sWd[idx] = wd[((ic*32 + oc) << 4) + r];   // IOHW: (ic, oc, ki, kj)
    }
    __syncthreads();
    float* ob = out + (size_t)b*BSTRIDE + (size_t)(128 + oc)*4096;
    for (int s = 0; s < 16; ++s) {
        const int p  = tid + (s << 8);
        const int i  = p >> 6, jc = p & 63;
        const int si = i >> 2, ki = i & 3, sj = jc >> 2, kj = jc & 3;
        float acc = 0.f;
        #pragma unroll
        for (int ic = 0; ic < 32; ++ic)
            acc += sO[ic*256 + si*16 + sj] * sWd[ic*16 + ki*4 + kj];
        ob[p] = acc;
    }
}

// DIAG: linear grid-stride read of ALL of T, x4 reps. Gives this chip's
// true streaming floor for T (expected ~6.3 TB/s). Written to ws scratch.
__global__ __launch_bounds__(256) void diag_stream(
    const float* __restrict__ Tm, float* __restrict__ o)
{
    const int tid = blockIdx.x*256 + threadIdx.x;   // 524288 threads
    const float4* p = (const float4*)Tm;            // 25165824 float4s
    float4 s = make_float4(0.f, 0.f, 0.f, 0.f);
    for (int rep = 0; rep < 4; ++rep) {
        for (size_t i = tid; i < 25165824u; i += 524288u) {  // 48 sweeps
            const float4 v = p[i];
            s.x += v.x; s.y += v.y; s.z += v.z; s.w += v.w;
        }
    }
    o[tid] = s.x + s.y + s.z + s.w;
}

extern "C" void kernel_launch(void* const* d_in, const int* in_sizes, int n_in,
                              void* d_out, int out_size, void* d_ws, size_t ws_size,
                              hipStream_t stream) {
    const float* x  = (const float*)d_in[0];
    const float* wc = (const float*)d_in[1];
    const float* Tm = (const float*)d_in[2];
    const float* wd = (const float*)d_in[3];
    float* out  = (float*)d_out;
    float* At   = (float*)d_ws;                        // 96 KB @ 0
    float* diag = (float*)((char*)d_ws + (1 << 20));   // 2 MB @ 1 MB
    float* outS = (float*)((char*)d_ws + (4 << 20));   // 1 MB @ 4 MB

    k1_conv_copy<<<NB*TSP, 256, 0, stream>>>(x, wc, out, At);                   // 512 blocks
    k2_gemm    <<<NCOL/512, 512, D_IN*32*sizeof(float), stream>>>(At, Tm, out); // 256 blocks, x3
    k3_pairs   <<<D_OUT/32, 256, 32*32*17*sizeof(float), stream>>>(out, outS);  // 256 blocks
    k4_deconv  <<<NB*OUTF, 256, 0, stream>>>(outS, wd, out);                    // 1024 blocks
    diag_stream<<<2048, 256, 0, stream>>>(Tm, diag);                            // probe, x4
}

// Round 11
// 180.700 us; speedup vs baseline: 3.9268x; 3.9268x over previous
//
#include <hip/hip_runtime.h>

// Problem constants
#define NB      32      // batch
#define INF     128     // in_flt
#define NPIX    64      // N
#define TSP     16      // t
#define OUTF    32      // out_flt
#define FF      16      // intermediate features
#define D_IN    768     // 3*t*t
#define D_OUT   8192    // out_flt*t*t
#define NCOL    (D_OUT*FF)   // 131072
#define OUTCH   160     // in_flt + out_flt
#define BSTRIDE 655360  // 160*64*64 floats per batch in d_out
#define MOFF    524288  // 128*64*64: offset of out_a region per batch (M scratch)

// K1: fused strided conv (128ch,4x4,stride4 -> 3ch) + x->out concat copy.
// A written k-major: At[k*32 + b].
__global__ __launch_bounds__(256) void k1_conv_copy(
    const float* __restrict__ x, const float* __restrict__ wc,
    float* __restrict__ out, float* __restrict__ At)
{
    __shared__ float sW[3*128*16];     // w_conv, 24 KB
    __shared__ float sP[16][16][3];    // partials [icg][j][c3]
    const int b   = blockIdx.x >> 4;
    const int oi  = blockIdx.x & 15;
    const int tid = threadIdx.x;
    for (int idx = tid; idx < 6144; idx += 256) sW[idx] = wc[idx];
    __syncthreads();
    const int icg = tid >> 4;          // 0..15 -> ic block of 8
    const int j   = tid & 15;          // output col
    float a0 = 0.f, a1 = 0.f, a2 = 0.f;
    for (int ic8 = 0; ic8 < 8; ++ic8) {
        const int ic = icg*8 + ic8;
        #pragma unroll
        for (int ki = 0; ki < 4; ++ki) {
            const int row = 4*oi + ki;
            const float4 xv = *(const float4*)(x + ((size_t)(b*INF+ic)*NPIX + row)*NPIX + 4*j);
            *(float4*)(out + ((size_t)(b*OUTCH+ic)*NPIX + row)*NPIX + 4*j) = xv;
            const float* w0 = sW + ((0*INF+ic)*4 + ki)*4;
            const float* w1 = sW + ((1*INF+ic)*4 + ki)*4;
            const float* w2 = sW + ((2*INF+ic)*4 + ki)*4;
            a0 += xv.x*w0[0] + xv.y*w0[1] + xv.z*w0[2] + xv.w*w0[3];
            a1 += xv.x*w1[0] + xv.y*w1[1] + xv.z*w1[2] + xv.w*w1[3];
            a2 += xv.x*w2[0] + xv.y*w2[1] + xv.z*w2[2] + xv.w*w2[3];
        }
    }
    sP[icg][j][0] = a0; sP[icg][j][1] = a1; sP[icg][j][2] = a2;
    __syncthreads();
    if (tid < 48) {
        const int c3 = tid >> 4, jj = tid & 15;
        float s = 0.f;
        #pragma unroll
        for (int g = 0; g < 16; ++g) s += sP[g][jj][c3];
        const int k = c3*256 + oi*16 + jj;    // reshape(3,16,16) C-order
        At[k*32 + b] = s;
    }
}

// K2 v11: waves split K, not batches. R10 evidence: warm replays (46 MB
// HBM, T L3-resident) run EXACTLY as slow as cold (646 MB) -> k2 is bound
// by per-instruction vector-memory processing (TA/L1 line expansion),
// amplified 4x by T-column sharing across bg-waves. Fix: wave w owns k-slice
// [w*96,(w+1)*96) of ONE 256-col range -> every T element loaded once by
// one lane (redundancy 1x, T-load instrs per CU /8). Lane accumulates ALL
// 32 batches: acc[32][4] (128 VGPR). A-loads are wave-uniform float4s off a
// readfirstlane'd base -> scalar K$ path, no VMEM, no LDS in the main loop.
// Cross-wave reduction via 64 KB LDS epilogue, layout [w][r][lane]
// (conflict-free writes and reads, coalesced 1KB stores per r-group).
__global__ __launch_bounds__(512) void k2_gemm(
    const float* __restrict__ At, const float* __restrict__ Tm,
    float* __restrict__ out)
{
    extern __shared__ float4 sR[];             // [8][8][64] float4 = 64 KB
    const int tid  = threadIdx.x;
    const int w    = tid >> 6;                 // wave 0..7
    const int lane = tid & 63;
    const int col4 = blockIdx.x*256 + lane*4;  // unique col per lane
    const int kbase = __builtin_amdgcn_readfirstlane(w) * 96;  // provably uniform

    float acc[32][4];
    #pragma unroll
    for (int i = 0; i < 32; ++i)
        #pragma unroll
        for (int j = 0; j < 4; ++j) acc[i][j] = 0.f;

    const float* tp = Tm + (size_t)kbase*NCOL + col4;
    const float* ap = At + kbase*32;           // wave-uniform -> s_load path

#define TLD(KK) (*(const float4*)(tp + (size_t)(KK)*NCOL))
#define FMG(G, AV, T4) { \
  acc[(G)*4+0][0]+=AV.x*T4.x; acc[(G)*4+0][1]+=AV.x*T4.y; acc[(G)*4+0][2]+=AV.x*T4.z; acc[(G)*4+0][3]+=AV.x*T4.w; \
  acc[(G)*4+1][0]+=AV.y*T4.x; acc[(G)*4+1][1]+=AV.y*T4.y; acc[(G)*4+1][2]+=AV.y*T4.z; acc[(G)*4+1][3]+=AV.y*T4.w; \
  acc[(G)*4+2][0]+=AV.z*T4.x; acc[(G)*4+2][1]+=AV.z*T4.y; acc[(G)*4+2][2]+=AV.z*T4.z; acc[(G)*4+2][3]+=AV.z*T4.w; \
  acc[(G)*4+3][0]+=AV.w*T4.x; acc[(G)*4+3][1]+=AV.w*T4.y; acc[(G)*4+3][2]+=AV.w*T4.z; acc[(G)*4+3][3]+=AV.w*T4.w; }
#define ALD(J) \
    const float4 a0 = *(const float4*)(ap + (k0+(J))*32 +  0); \
    const float4 a1 = *(const float4*)(ap + (k0+(J))*32 +  4); \
    const float4 a2 = *(const float4*)(ap + (k0+(J))*32 +  8); \
    const float4 a3 = *(const float4*)(ap + (k0+(J))*32 + 12); \
    const float4 a4 = *(const float4*)(ap + (k0+(J))*32 + 16); \
    const float4 a5 = *(const float4*)(ap + (k0+(J))*32 + 20); \
    const float4 a6 = *(const float4*)(ap + (k0+(J))*32 + 24); \
    const float4 a7 = *(const float4*)(ap + (k0+(J))*32 + 28);
#define STEP(J, RT) { ALD(J) \
    FMG(0,a0,RT) FMG(1,a1,RT) FMG(2,a2,RT) FMG(3,a3,RT) \
    FMG(4,a4,RT) FMG(5,a5,RT) FMG(6,a6,RT) FMG(7,a7,RT) \
    RT = TLD(k0 + 4 + (J)); }
#define STEPE(J, RT) { ALD(J) \
    FMG(0,a0,RT) FMG(1,a1,RT) FMG(2,a2,RT) FMG(3,a3,RT) \
    FMG(4,a4,RT) FMG(5,a5,RT) FMG(6,a6,RT) FMG(7,a7,RT) }

    float4 r0=TLD(0), r1=TLD(1), r2=TLD(2), r3=TLD(3);   // depth-4 T ring

    int k0 = 0;
    for (; k0 < 92; k0 += 4) {
        STEP(0, r0) STEP(1, r1) STEP(2, r2) STEP(3, r3)
    }
    // epilogue: k0 == 92, consume only (no prefetch past k=95)
    STEPE(0, r0) STEPE(1, r1) STEPE(2, r2) STEPE(3, r3)
#undef STEPE
#undef STEP
#undef ALD
#undef FMG
#undef TLD

    // Cross-wave k-reduction: 4 chunks of 8 batches. sR[w][r][lane].
    for (int c = 0; c < 4; ++c) {
        #pragma unroll
        for (int r = 0; r < 8; ++r)
            sR[(w*8 + r)*64 + lane] = make_float4(
                acc[c*8+r][0], acc[c*8+r][1], acc[c*8+r][2], acc[c*8+r][3]);
        __syncthreads();
        const int r2 = tid >> 6, lane2 = tid & 63;   // thread -> (batch-in-chunk, col)
        float4 s = sR[r2*64 + lane2];                // w=0
        #pragma unroll
        for (int ww = 1; ww < 8; ++ww) {
            const float4 v = sR[(ww*8 + r2)*64 + lane2];
            s.x += v.x; s.y += v.y; s.z += v.z; s.w += v.w;
        }
        *(float4*)(out + (size_t)(c*8 + r2)*BSTRIDE + MOFF + blockIdx.x*256 + lane2*4) = s;
        __syncthreads();
    }
}

// K3: out[j,d] = sum_i exp(-sum_f |M[i,d,f]-M[j,d,f]|) - 1. (M in d_out slots)
__global__ __launch_bounds__(256) void k3_pairs(
    const float* __restrict__ outM, float* __restrict__ outS)
{
    extern __shared__ float sM[];      // 32*32*17 floats
    const int tid = threadIdx.x;
    const int dd0 = blockIdx.x * 32;
    for (int idx = tid; idx < 32*32*16; idx += 256) {
        const int i = idx >> 9, rem = idx & 511, d = rem >> 4, f = rem & 15;
        sM[(i*32 + d)*17 + f] =
            outM[(size_t)i*BSTRIDE + MOFF + (size_t)(dd0 + d)*16 + f];
    }
    __syncthreads();
    const int j = tid >> 3;
    for (int q = 0; q < 4; ++q) {
        const int d = (tid & 7) + q*8;
        float mj[16];
        const float* pj = sM + (j*32 + d)*17;
        #pragma unroll
        for (int f = 0; f < 16; ++f) mj[f] = pj[f];
        float acc = 0.f;
        for (int i = 0; i < 32; ++i) {
            const float* pi = sM + (i*32 + d)*17;
            float dist = 0.f;
            #pragma unroll
            for (int f = 0; f < 16; ++f) dist += fabsf(pi[f] - mj[f]);
            acc += __expf(-dist);
        }
        outS[(size_t)j*D_OUT + dd0 + d] = acc - 1.0f;
    }
}

// K4: ConvTranspose2d, stride==kernel -> no overlap.
__global__ __launch_bounds__(256) void k4_deconv(
    const float* __restrict__ outS, const float* __restrict__ wd,
    float* __restrict__ out)
{
    __shared__ float sO[32*256];       // [ic][si*16+sj]
    __shared__ float sWd[32*16];       // [ic][ki*4+kj]
    const int b   = blockIdx.x >> 5;
    const int oc  = blockIdx.x & 31;
    const int tid = threadIdx.x;
    for (int idx = tid; idx < 8192; idx += 256) sO[idx] = outS[(size_t)b*D_OUT + idx];
    for (int idx = tid; idx < 512; idx += 256) {
        const int ic = idx >> 4, r = idx & 15;
        sWd[idx] = wd[((ic*32 + oc) << 4) + r];   // IOHW: (ic, oc, ki, kj)
    }
    __syncthreads();
    float* ob = out + (size_t)b*BSTRIDE + (size_t)(128 + oc)*4096;
    for (int s = 0; s < 16; ++s) {
        const int p  = tid + (s << 8);
        const int i  = p >> 6, jc = p & 63;
        const int si = i >> 2, ki = i & 3, sj = jc >> 2, kj = jc & 3;
        float acc = 0.f;
        #pragma unroll
        for (int ic = 0; ic < 32; ++ic)
            acc += sO[ic*256 + si*16 + sj] * sWd[ic*16 + ki*4 + kj];
        ob[p] = acc;
    }
}

extern "C" void kernel_launch(void* const* d_in, const int* in_sizes, int n_in,
                              void* d_out, int out_size, void* d_ws, size_t ws_size,
                              hipStream_t stream) {
    const float* x  = (const float*)d_in[0];
    const float* wc = (const float*)d_in[1];
    const float* Tm = (const float*)d_in[2];
    const float* wd = (const float*)d_in[3];
    float* out  = (float*)d_out;
    float* At   = (float*)d_ws;                        // 96 KB @ 0
    float* outS = (float*)((char*)d_ws + (1 << 20));   // 1 MB @ 1 MB

    k1_conv_copy<<<NB*TSP, 256, 0, stream>>>(x, wc, out, At);                   // 512 blocks
    k2_gemm    <<<NCOL/256, 512, 65536, stream>>>(At, Tm, out);                 // 512 blocks
    k3_pairs   <<<D_OUT/32, 256, 32*32*17*sizeof(float), stream>>>(out, outS);  // 256 blocks
    k4_deconv  <<<NB*OUTF, 256, 0, stream>>>(outS, wd, out);                    // 1024 blocks
}